// Round 5
// baseline (114.881 us; speedup 1.0000x reference)
//
#include <hip/hip_runtime.h>
#include <hip/hip_bf16.h>

#define H 2048
#define BN 64
#define TT 4096
#define BB 4
#define KK 128
#define CP_BLOCKS 2048
#define RPB 8

typedef float vf4 __attribute__((ext_vector_type(4)));

// ---------------------------------------------------------------------------
// Kernel 1: fused  out = x  +  partial logits.
// Half-row (1024 floats) per wave-iteration; 2048 blocks, lean VGPR so
// 8 blocks/CU co-resident (32 waves/CU). Non-temporal stores for `out`
// (never re-read) so x stays L3-resident. lpart[2*row+half] = partial dot.
// ---------------------------------------------------------------------------
__global__ __launch_bounds__(256, 8) void copy_logits_kernel(
    const float* __restrict__ x, const float* __restrict__ Wg,
    float* __restrict__ out, float* __restrict__ lpart, int nhalf) {
    const int lane = threadIdx.x & 63;
    const int wv   = (blockIdx.x * 256 + threadIdx.x) >> 6;
    const int nw   = CP_BLOCKS * 4;                 // 8192 waves
    // this wave only ever touches half-rows of parity (wv & 1)
    const vf4* w4 = (const vf4*)Wg + (size_t)(wv & 1) * 256;
    vf4 w[4];
#pragma unroll
    for (int i = 0; i < 4; ++i) w[i] = w4[lane + 64 * i];

    for (int hr = wv; hr < nhalf; hr += nw) {
        const vf4* xs = (const vf4*)x + (size_t)hr * 256;
        vf4*       os = (vf4*)out + (size_t)hr * 256;
        vf4 a[4];
#pragma unroll
        for (int i = 0; i < 4; ++i) a[i] = xs[lane + 64 * i];
        float s0 = 0.f, s1 = 0.f, s2 = 0.f, s3 = 0.f;
#pragma unroll
        for (int i = 0; i < 4; ++i) {
            __builtin_nontemporal_store(a[i], &os[lane + 64 * i]);
            s0 = fmaf(a[i].x, w[i].x, s0);
            s1 = fmaf(a[i].y, w[i].y, s1);
            s2 = fmaf(a[i].z, w[i].z, s2);
            s3 = fmaf(a[i].w, w[i].w, s3);
        }
        float acc = (s0 + s1) + (s2 + s3);
#pragma unroll
        for (int off = 32; off > 0; off >>= 1) acc += __shfl_down(acc, off);
        if (lane == 0) lpart[hr] = acc;
    }
}

// ---------------------------------------------------------------------------
// Kernel 2: per batch, top-K -> compact index list. Keys built from the two
// half-row partials (fixed order -> deterministic). Radix select; ties in
// ascending index order (lax.top_k semantics).
// ---------------------------------------------------------------------------
__global__ __launch_bounds__(256) void topk_idx_kernel(
    const float* __restrict__ lpart, int* __restrict__ idxlist) {
    __shared__ unsigned keys[TT];
    __shared__ int wsum[4];
    __shared__ int gtp[256], eqp[256];
    const int tid = threadIdx.x;
    const int b   = blockIdx.x;
    const float* lp = lpart + (size_t)b * TT * 2;

    for (int i = tid; i < TT; i += 256) {
        float v = lp[2 * i] + lp[2 * i + 1];
        unsigned u = __float_as_uint(v);
        keys[i] = (u & 0x80000000u) ? ~u : (u | 0x80000000u);
    }
    __syncthreads();

    unsigned prefix = 0;
    int k = KK;
    for (int bit = 31; bit >= 0; --bit) {
        unsigned ref = (prefix >> bit) | 1u;
        int c = 0;
        for (int i = tid; i < TT; i += 256) c += ((keys[i] >> bit) == ref);
#pragma unroll
        for (int off = 32; off > 0; off >>= 1) c += __shfl_down(c, off);
        if ((tid & 63) == 0) wsum[tid >> 6] = c;
        __syncthreads();
        int total = wsum[0] + wsum[1] + wsum[2] + wsum[3];
        __syncthreads();
        if (total >= k) prefix |= (1u << bit);
        else            k -= total;
    }

    const int per = TT / 256, i0 = tid * per, i1 = i0 + per;
    int cgt = 0, ceq = 0;
    for (int i = i0; i < i1; ++i) {
        cgt += (keys[i] > prefix);
        ceq += (keys[i] == prefix);
    }
    gtp[tid] = cgt; eqp[tid] = ceq;
    __syncthreads();
    if (tid == 0) {
        int sg = 0, se = 0;
        for (int t = 0; t < 256; ++t) {
            int a = gtp[t]; gtp[t] = sg; sg += a;
            int c = eqp[t]; eqp[t] = se; se += c;
        }
        wsum[0] = sg;
    }
    __syncthreads();
    const int total_gt = wsum[0];
    const int need_eq  = KK - total_gt;
    int g = gtp[tid], e = eqp[tid];
    int* dst = idxlist + b * KK;
    for (int i = i0; i < i1; ++i) {
        if (keys[i] > prefix)       dst[g++] = b * TT + i;
        else if (keys[i] == prefix) { if (e < need_eq) dst[total_gt + e] = b * TT + i; e++; }
    }
}

// ---------------------------------------------------------------------------
// Kernel 3: adapter, RPB=8 rows per block (64 blocks x 512 threads).
// Weights read once per block (streamed via L2/L3). Down-proj uses
// v_readlane register broadcast; up-proj one float4 column per thread.
// ---------------------------------------------------------------------------
__global__ __launch_bounds__(512) void adapter_kernel(
    const float* __restrict__ x, const float* __restrict__ Wd,
    const float* __restrict__ bd, const float* __restrict__ Wu,
    const float* __restrict__ bu, const int* __restrict__ idxlist,
    float* __restrict__ out) {
    __shared__ float hp[8][RPB][BN];   // [h-group][row][j]  16 KB
    __shared__ float hs[RPB][BN];      //                     2 KB
    const int tid  = threadIdx.x;
    const int lane = tid & 63;         // j-column in down-proj
    const int g    = tid >> 6;         // h-group (256 h each)

    int rows[RPB];
#pragma unroll
    for (int r = 0; r < RPB; ++r) rows[r] = idxlist[blockIdx.x * RPB + r];

    // stage x chunks: lane holds h = g*256 + k*64 + lane
    float xr[RPB][4];
#pragma unroll
    for (int r = 0; r < RPB; ++r) {
        const float* p = x + (size_t)rows[r] * H + g * 256 + lane;
#pragma unroll
        for (int k = 0; k < 4; ++k) xr[r][k] = p[k * 64];
    }

    float acc[RPB];
#pragma unroll
    for (int r = 0; r < RPB; ++r) acc[r] = 0.f;
    const float* wdp = Wd + (size_t)(g * 256) * BN + lane;
#pragma unroll
    for (int k = 0; k < 4; ++k) {
#pragma unroll 8
        for (int l = 0; l < 64; ++l) {
            float wv = wdp[(size_t)(k * 64 + l) * BN];
#pragma unroll
            for (int r = 0; r < RPB; ++r)
                acc[r] = fmaf(__int_as_float(__builtin_amdgcn_readlane(
                                  __float_as_int(xr[r][k]), l)), wv, acc[r]);
        }
    }
#pragma unroll
    for (int r = 0; r < RPB; ++r) hp[g][r][lane] = acc[r];
    __syncthreads();

    {   // 512 threads == RPB*BN: combine partials + bias + relu
        int r = tid >> 6, jj = tid & 63;
        float v = bd[jj];
#pragma unroll
        for (int gg = 0; gg < 8; ++gg) v += hp[gg][r][jj];
        hs[r][jj] = v > 0.f ? v : 0.f;
    }
    __syncthreads();

    // up-proj: thread owns float4 column `tid` (512 float4 = H)
    const float4* Wu4 = (const float4*)Wu;
    float4 yb = ((const float4*)bu)[tid];
    float4 y[RPB];
#pragma unroll
    for (int r = 0; r < RPB; ++r) y[r] = yb;
    for (int jj = 0; jj < BN; ++jj) {
        float4 wv = Wu4[(size_t)jj * (H / 4) + tid];
#pragma unroll
        for (int r = 0; r < RPB; ++r) {
            float h = hs[r][jj];
            y[r].x = fmaf(h, wv.x, y[r].x); y[r].y = fmaf(h, wv.y, y[r].y);
            y[r].z = fmaf(h, wv.z, y[r].z); y[r].w = fmaf(h, wv.w, y[r].w);
        }
    }
#pragma unroll
    for (int r = 0; r < RPB; ++r) {
        const float4* xr4 = (const float4*)(x + (size_t)rows[r] * H);
        float4*       o4  = (float4*)(out + (size_t)rows[r] * H);
        float4 xa = xr4[tid];
        o4[tid] = make_float4(xa.x + y[r].x, xa.y + y[r].y,
                              xa.z + y[r].z, xa.w + y[r].w);
    }
}

// ---------------------------------------------------------------------------
extern "C" void kernel_launch(void* const* d_in, const int* in_sizes, int n_in,
                              void* d_out, int out_size, void* d_ws, size_t ws_size,
                              hipStream_t stream) {
    const float* x  = (const float*)d_in[0];
    const float* Wd = (const float*)d_in[1];
    const float* bd = (const float*)d_in[2];
    const float* Wu = (const float*)d_in[3];
    const float* bu = (const float*)d_in[4];
    const float* Wg = (const float*)d_in[5];
    float* out = (float*)d_out;

    const int nrows = in_sizes[0] / H;                 // B*T = 16384
    const int nhalf = nrows * 2;
    float* lpart   = (float*)d_ws;                     // nhalf floats
    int*   idxlist = (int*)((char*)d_ws + (size_t)nhalf * sizeof(float));

    copy_logits_kernel<<<CP_BLOCKS, 256, 0, stream>>>(x, Wg, out, lpart, nhalf);
    topk_idx_kernel<<<BB, 256, 0, stream>>>(lpart, idxlist);
    adapter_kernel<<<(BB * KK) / RPB, 512, 0, stream>>>(x, Wd, bd, Wu, bu, idxlist, out);
}

// Round 6
// 98.116 us; speedup vs baseline: 1.1709x; 1.1709x over previous
//
#include <hip/hip_runtime.h>
#include <hip/hip_bf16.h>

#define H 2048
#define BN 64
#define TT 4096
#define BB 4
#define KK 128
#define CP_BLOCKS 1024
#define RPB 4

typedef float vf4 __attribute__((ext_vector_type(4)));

// ---------------------------------------------------------------------------
// Kernel 1: fused  out = x  +  logits = x @ Wg.
// Read stream via global_load_lds (no dest VGPRs -> load stream decoupled
// from store stream's registers). One row (8KB) per wave per iteration;
// per-wave private 8KB LDS buffer; 1024 blocks x 4 waves = 4096 waves,
// exactly 4 rows/wave. NT stores for out (never re-read).
// ---------------------------------------------------------------------------
__global__ __launch_bounds__(256) void copy_logits_kernel(
    const float* __restrict__ x, const float* __restrict__ Wg,
    float* __restrict__ out, float* __restrict__ logits, int nrows) {
    __shared__ char buf[4][8192];
    const int lane = threadIdx.x & 63;
    const int wid  = threadIdx.x >> 6;          // wave within block (uniform)
    char* bw = buf[wid];
    const int wv = blockIdx.x * 4 + wid;        // global wave id
    const vf4* w4 = (const vf4*)Wg;             // 8KB, L1-resident

    for (int row = wv; row < nrows; row += CP_BLOCKS * 4) {
        const float* xr = x + ((size_t)row << 11);
        // issue 8 direct-to-LDS loads: 16B/lane, 1KB per instruction
#pragma unroll
        for (int i = 0; i < 8; ++i) {
            __builtin_amdgcn_global_load_lds(
                (const __attribute__((address_space(1))) void*)(xr + ((i << 6) + lane) * 4),
                (__attribute__((address_space(3))) void*)(bw + i * 1024),
                16, 0, 0);
        }
        asm volatile("s_waitcnt vmcnt(0)" ::: "memory");

        const vf4* bv = (const vf4*)bw;
        vf4* orow = (vf4*)(out + ((size_t)row << 11));
        float s0 = 0.f, s1 = 0.f, s2 = 0.f, s3 = 0.f;
#pragma unroll
        for (int i = 0; i < 8; ++i) {
            vf4 a  = bv[(i << 6) + lane];       // contiguous 16B/lane: conflict-free
            vf4 wv4 = w4[(i << 6) + lane];
            __builtin_nontemporal_store(a, &orow[(i << 6) + lane]);
            s0 = fmaf(a.x, wv4.x, s0);
            s1 = fmaf(a.y, wv4.y, s1);
            s2 = fmaf(a.z, wv4.z, s2);
            s3 = fmaf(a.w, wv4.w, s3);
        }
        float acc = (s0 + s1) + (s2 + s3);
#pragma unroll
        for (int off = 32; off > 0; off >>= 1) acc += __shfl_down(acc, off);
        if (lane == 0) logits[row] = acc;
    }
}

// ---------------------------------------------------------------------------
// Kernel 2: per batch, top-K -> compact index list (proven round-3 version).
// Radix select; ties in ascending index order (lax.top_k semantics).
// ---------------------------------------------------------------------------
__global__ __launch_bounds__(256) void topk_idx_kernel(
    const float* __restrict__ logits, int* __restrict__ idxlist) {
    __shared__ unsigned keys[TT];
    __shared__ int wsum[4];
    __shared__ int gtp[256], eqp[256];
    const int tid = threadIdx.x;
    const int b   = blockIdx.x;
    const float* lr = logits + (size_t)b * TT;

    for (int i = tid; i < TT; i += 256) {
        unsigned u = __float_as_uint(lr[i]);
        keys[i] = (u & 0x80000000u) ? ~u : (u | 0x80000000u);
    }
    __syncthreads();

    unsigned prefix = 0;
    int k = KK;
    for (int bit = 31; bit >= 0; --bit) {
        unsigned ref = (prefix >> bit) | 1u;
        int c = 0;
        for (int i = tid; i < TT; i += 256) c += ((keys[i] >> bit) == ref);
#pragma unroll
        for (int off = 32; off > 0; off >>= 1) c += __shfl_down(c, off);
        if ((tid & 63) == 0) wsum[tid >> 6] = c;
        __syncthreads();
        int total = wsum[0] + wsum[1] + wsum[2] + wsum[3];
        __syncthreads();
        if (total >= k) prefix |= (1u << bit);
        else            k -= total;
    }

    const int per = TT / 256, i0 = tid * per, i1 = i0 + per;
    int cgt = 0, ceq = 0;
    for (int i = i0; i < i1; ++i) {
        cgt += (keys[i] > prefix);
        ceq += (keys[i] == prefix);
    }
    gtp[tid] = cgt; eqp[tid] = ceq;
    __syncthreads();
    if (tid == 0) {
        int sg = 0, se = 0;
        for (int t = 0; t < 256; ++t) {
            int a = gtp[t]; gtp[t] = sg; sg += a;
            int c = eqp[t]; eqp[t] = se; se += c;
        }
        wsum[0] = sg;
    }
    __syncthreads();
    const int total_gt = wsum[0];
    const int need_eq  = KK - total_gt;
    int g = gtp[tid], e = eqp[tid];
    int* dst = idxlist + b * KK;
    for (int i = i0; i < i1; ++i) {
        if (keys[i] > prefix)       dst[g++] = b * TT + i;
        else if (keys[i] == prefix) { if (e < need_eq) dst[total_gt + e] = b * TT + i; e++; }
    }
}

// ---------------------------------------------------------------------------
// Kernel 3: adapter, RPB=4 rows per block (128 blocks x 512 threads) —
// proven round-3 config. Down-proj via v_readlane register broadcast;
// up-proj one float4 column per thread.
// ---------------------------------------------------------------------------
__global__ __launch_bounds__(512) void adapter_kernel(
    const float* __restrict__ x, const float* __restrict__ Wd,
    const float* __restrict__ bd, const float* __restrict__ Wu,
    const float* __restrict__ bu, const int* __restrict__ idxlist,
    float* __restrict__ out) {
    __shared__ float hp[8][RPB][BN];   // [h-group][row][j]  8 KB
    __shared__ float hs[RPB][BN];      //                    1 KB
    const int tid  = threadIdx.x;
    const int lane = tid & 63;         // j-column in down-proj
    const int g    = tid >> 6;         // h-group (256 h each)

    int rows[RPB];
#pragma unroll
    for (int r = 0; r < RPB; ++r) rows[r] = idxlist[blockIdx.x * RPB + r];

    // stage x chunks: lane holds h = g*256 + k*64 + lane
    float xr[RPB][4];
#pragma unroll
    for (int r = 0; r < RPB; ++r) {
        const float* p = x + (size_t)rows[r] * H + g * 256 + lane;
#pragma unroll
        for (int k = 0; k < 4; ++k) xr[r][k] = p[k * 64];
    }

    float acc[RPB];
#pragma unroll
    for (int r = 0; r < RPB; ++r) acc[r] = 0.f;
    const float* wdp = Wd + (size_t)(g * 256) * BN + lane;
#pragma unroll
    for (int k = 0; k < 4; ++k) {
#pragma unroll 8
        for (int l = 0; l < 64; ++l) {
            float wv = wdp[(size_t)(k * 64 + l) * BN];
#pragma unroll
            for (int r = 0; r < RPB; ++r)
                acc[r] = fmaf(__int_as_float(__builtin_amdgcn_readlane(
                                  __float_as_int(xr[r][k]), l)), wv, acc[r]);
        }
    }
#pragma unroll
    for (int r = 0; r < RPB; ++r) hp[g][r][lane] = acc[r];
    __syncthreads();

    if (tid < RPB * BN) {   // combine partials + bias + relu
        int r = tid >> 6, jj = tid & 63;
        float v = bd[jj];
#pragma unroll
        for (int gg = 0; gg < 8; ++gg) v += hp[gg][r][jj];
        hs[r][jj] = v > 0.f ? v : 0.f;
    }
    __syncthreads();

    // up-proj: thread owns float4 column `tid` (512 float4 = H)
    const float4* Wu4 = (const float4*)Wu;
    float4 yb = ((const float4*)bu)[tid];
    float4 y[RPB];
#pragma unroll
    for (int r = 0; r < RPB; ++r) y[r] = yb;
    for (int jj = 0; jj < BN; ++jj) {
        float4 wv = Wu4[(size_t)jj * (H / 4) + tid];
#pragma unroll
        for (int r = 0; r < RPB; ++r) {
            float h = hs[r][jj];
            y[r].x = fmaf(h, wv.x, y[r].x); y[r].y = fmaf(h, wv.y, y[r].y);
            y[r].z = fmaf(h, wv.z, y[r].z); y[r].w = fmaf(h, wv.w, y[r].w);
        }
    }
#pragma unroll
    for (int r = 0; r < RPB; ++r) {
        const float4* xr4 = (const float4*)(x + (size_t)rows[r] * H);
        float4*       o4  = (float4*)(out + (size_t)rows[r] * H);
        float4 xa = xr4[tid];
        o4[tid] = make_float4(xa.x + y[r].x, xa.y + y[r].y,
                              xa.z + y[r].z, xa.w + y[r].w);
    }
}

// ---------------------------------------------------------------------------
extern "C" void kernel_launch(void* const* d_in, const int* in_sizes, int n_in,
                              void* d_out, int out_size, void* d_ws, size_t ws_size,
                              hipStream_t stream) {
    const float* x  = (const float*)d_in[0];
    const float* Wd = (const float*)d_in[1];
    const float* bd = (const float*)d_in[2];
    const float* Wu = (const float*)d_in[3];
    const float* bu = (const float*)d_in[4];
    const float* Wg = (const float*)d_in[5];
    float* out = (float*)d_out;

    const int nrows = in_sizes[0] / H;                 // B*T = 16384
    float* logits  = (float*)d_ws;                     // nrows floats
    int*   idxlist = (int*)((char*)d_ws + (size_t)nrows * sizeof(float));

    copy_logits_kernel<<<CP_BLOCKS, 256, 0, stream>>>(x, Wg, out, logits, nrows);
    topk_idx_kernel<<<BB, 256, 0, stream>>>(logits, idxlist);
    adapter_kernel<<<(BB * KK) / RPB, 512, 0, stream>>>(x, Wd, bd, Wu, bu, idxlist, out);
}